// Round 3
// baseline (2072.997 us; speedup 1.0000x reference)
//
#include <hip/hip_runtime.h>
#include <cmath>

#define NS 16384   // samples
#define LS 4096    // memory slots
#define DF 1024    // feature dim
#define SHRINK_T 0.0025f
#define EPS_T 1e-12f

// ---------------- K0: centroid = mean(weight, axis=0) ----------------
__global__ void centroid_kernel(const float* __restrict__ w, float* __restrict__ cen) {
    int c = blockIdx.x * 256 + threadIdx.x;
    if (c >= DF) return;
    float acc = 0.f;
    for (int l = 0; l < LS; ++l) acc += w[(size_t)l * DF + c];
    cen[c] = acc * (1.0f / (float)LS);
}

// ---------------- K1: S = x[r0:r0+rows] @ w^T (fp32 vector ALU) ----------------
#define BM 128
#define BN 128
#define BK 16
#define LSTR 20

__global__ __launch_bounds__(256, 2) void gemm_kernel(
    const float* __restrict__ x, const float* __restrict__ w,
    float* __restrict__ S, int r0, int rowsChunk)
{
    __shared__ float As[BM * LSTR];
    __shared__ float Bs[BN * LSTR];
    const int tid = threadIdx.x;
    const int tx = tid & 15;
    const int ty = tid >> 4;
    const int rowBase = r0 + blockIdx.y * BM;       // global sample row
    const int colBase = blockIdx.x * BN;            // memory-slot col

    float acc[8][8];
#pragma unroll
    for (int i = 0; i < 8; ++i)
#pragma unroll
        for (int j = 0; j < 8; ++j) acc[i][j] = 0.f;

    const int lrow = tid >> 2;       // 0..63
    const int lc4 = (tid & 3) * 4;   // 0,4,8,12

    for (int k0 = 0; k0 < DF; k0 += BK) {
#pragma unroll
        for (int h = 0; h < 2; ++h) {
            int row = lrow + h * 64;
            int gr = rowBase + row;
            if (gr >= NS) gr = NS - 1;   // safe clamp (stores are guarded)
            float4 va = *reinterpret_cast<const float4*>(&x[(size_t)gr * DF + k0 + lc4]);
            float4 vb = *reinterpret_cast<const float4*>(&w[(size_t)(colBase + row) * DF + k0 + lc4]);
            *reinterpret_cast<float4*>(&As[row * LSTR + lc4]) = va;
            *reinterpret_cast<float4*>(&Bs[row * LSTR + lc4]) = vb;
        }
        __syncthreads();
#pragma unroll
        for (int kk = 0; kk < BK; ++kk) {
            float a[8], b[8];
#pragma unroll
            for (int i = 0; i < 8; ++i) a[i] = As[(ty + 16 * i) * LSTR + kk];
#pragma unroll
            for (int j = 0; j < 8; ++j) b[j] = Bs[(tx + 16 * j) * LSTR + kk];
#pragma unroll
            for (int i = 0; i < 8; ++i)
#pragma unroll
                for (int j = 0; j < 8; ++j)
                    acc[i][j] = fmaf(a[i], b[j], acc[i][j]);
        }
        __syncthreads();
    }
    const int srow0 = blockIdx.y * BM;  // chunk-local
#pragma unroll
    for (int i = 0; i < 8; ++i) {
        int rr = srow0 + ty + 16 * i;
        if (rr < rowsChunk) {
            float* sp = S + (size_t)rr * LS + colBase + tx;
#pragma unroll
            for (int j = 0; j < 8; ++j) sp[16 * j] = acc[i][j];
        }
    }
}

// ---------------- K2: per-row softmax/shrink/norm + all outputs (f32 out) ----------------
__global__ __launch_bounds__(256) void pass2_kernel(
    const float* __restrict__ S, const float* __restrict__ x,
    const float* __restrict__ w, const float* __restrict__ cen,
    float* __restrict__ out, int r0)
{
    constexpr int T = 256;
    constexpr int PER = LS / T;  // 16
    __shared__ float att_lds[LS];   // 16 KB: the normalized att row
    __shared__ float red[T];
    __shared__ int redi[T];

    const int t = threadIdx.x;
    const size_t row = (size_t)r0 + blockIdx.x;
    const float* srow = S + (size_t)blockIdx.x * (size_t)LS;

    float* const out_output = out;
    float* const out_att  = out + (size_t)NS * DF;
    float* const out_nl   = out + (size_t)NS * DF + (size_t)NS * LS;
    float* const out_nl2  = out + (size_t)2 * NS * DF + (size_t)NS * LS;
    float* const out_mask = out + (size_t)3 * NS * DF + (size_t)NS * LS;

    // ---- load logits, row max ----
    float sv[PER];
    float mx = -INFINITY;
#pragma unroll
    for (int i = 0; i < PER; ++i) {
        sv[i] = srow[i * T + t];
        mx = fmaxf(mx, sv[i]);
    }
    red[t] = mx;
    __syncthreads();
    for (int off = 128; off >= 1; off >>= 1) {
        if (t < off) red[t] = fmaxf(red[t], red[t + off]);
        __syncthreads();
    }
    const float m = red[0];
    __syncthreads();

    // ---- exp, Z ----
    float zs = 0.f;
#pragma unroll
    for (int i = 0; i < PER; ++i) {
        sv[i] = expf(sv[i] - m);
        zs += sv[i];
    }
    red[t] = zs;
    __syncthreads();
    for (int off = 128; off >= 1; off >>= 1) {
        if (t < off) red[t] += red[t + off];
        __syncthreads();
    }
    const float Z = red[0];
    __syncthreads();

    // ---- softmax -> hard_shrink_relu -> l1 ----
    float l1 = 0.f;
#pragma unroll
    for (int i = 0; i < PER; ++i) {
        float a = sv[i] / Z;
        float r = a - SHRINK_T;
        float v = (r > 0.f) ? (r * a) / (r + EPS_T) : 0.f;
        sv[i] = v;
        l1 += v;
    }
    red[t] = l1;
    __syncthreads();
    for (int off = 128; off >= 1; off >>= 1) {
        if (t < off) red[t] += red[t + off];
        __syncthreads();
    }
    const float nrm = fmaxf(red[0], EPS_T);
    __syncthreads();

    // ---- normalize; stage row in LDS; write att; thread-local argmax/min ----
    float bv = -INFINITY; int bi = LS;
    float mn = INFINITY;
#pragma unroll
    for (int i = 0; i < PER; ++i) {
        float vn = sv[i] / nrm;
        sv[i] = vn;
        int j = i * T + t;
        att_lds[j] = vn;
        out_att[row * LS + j] = vn;
        if (vn > bv) { bv = vn; bi = j; }
        mn = fminf(mn, vn);
    }
    __syncthreads();   // att_lds complete

    // ---- argmax (first index on ties, matching np.argmax) ----
    red[t] = bv; redi[t] = bi;
    __syncthreads();
    for (int off = 128; off >= 1; off >>= 1) {
        if (t < off) {
            float ov = red[t + off]; int oi = redi[t + off];
            if (ov > red[t] || (ov == red[t] && oi < redi[t])) { red[t] = ov; redi[t] = oi; }
        }
        __syncthreads();
    }
    const int ind = redi[0];
    __syncthreads();

    // ---- row min ----
    red[t] = mn;
    __syncthreads();
    for (int off = 128; off >= 1; off >>= 1) {
        if (t < off) red[t] = fminf(red[t], red[t + off]);
        __syncthreads();
    }
    const float rowmin = red[0];
    __syncthreads();

    // ---- second argmax with att[ind] replaced by rowmin ----
    bv = -INFINITY; bi = LS;
#pragma unroll
    for (int i = 0; i < PER; ++i) {
        int j = i * T + t;
        float vv = (j == ind) ? rowmin : sv[i];
        if (vv > bv) { bv = vv; bi = j; }
    }
    red[t] = bv; redi[t] = bi;
    __syncthreads();
    for (int off = 128; off >= 1; off >>= 1) {
        if (t < off) {
            float ov = red[t + off]; int oi = redi[t + off];
            if (ov > red[t] || (ov == red[t] && oi < redi[t])) { red[t] = ov; redi[t] = oi; }
        }
        __syncthreads();
    }
    const int ind2 = redi[0];
    __syncthreads();

    // ---- output row = sum_k att[k] * w[k,:], wave-uniform ballot over LDS ----
    const int lane = t & 63;
    float oa[4] = {0.f, 0.f, 0.f, 0.f};
    for (int k0 = 0; k0 < LS; k0 += 64) {
        float av = att_lds[k0 + lane];
        unsigned long long msk = __ballot(av > 0.f);
        while (msk) {
            int b = __ffsll((unsigned long long)msk) - 1;
            msk &= msk - 1;
            float vv = att_lds[k0 + b];          // uniform LDS broadcast
            const float* wr = w + (size_t)(k0 + b) * DF;
#pragma unroll
            for (int q = 0; q < 4; ++q) oa[q] = fmaf(vv, wr[t + T * q], oa[q]);
        }
    }
#pragma unroll
    for (int q = 0; q < 4; ++q)
        out_output[row * DF + t + T * q] = oa[q];

    // ---- nl / nl2 gathers (exact f32 copies of weight rows) ----
    const float* w1 = w + (size_t)ind * DF;
    const float* w2 = w + (size_t)ind2 * DF;
#pragma unroll
    for (int q = 0; q < 4; ++q) {
        out_nl[row * DF + t + T * q]  = w1[t + T * q];
        out_nl2[row * DF + t + T * q] = w2[t + T * q];
    }

    // ---- distance mask ----
    float ds = 0.f;
#pragma unroll
    for (int q = 0; q < 4; ++q) {
        float d = x[row * DF + t + T * q] - cen[t + T * q];
        ds = fmaf(d, d, ds);
    }
    red[t] = ds;
    __syncthreads();
    for (int off = 128; off >= 1; off >>= 1) {
        if (t < off) red[t] += red[t + off];
        __syncthreads();
    }
    if (t == 0) {
        float dist = sqrtf(red[0]);
        out_mask[row] = (dist < 1.0f) ? 1.0f : 0.0f;
    }
}

// ---------------- host ----------------
extern "C" void kernel_launch(void* const* d_in, const int* in_sizes, int n_in,
                              void* d_out, int out_size, void* d_ws, size_t ws_size,
                              hipStream_t stream)
{
    const float* x = (const float*)d_in[0];
    const float* w = (const float*)d_in[1];
    float* out = (float*)d_out;

    float* cen = (float*)d_ws;        // DF floats
    float* S = cen + DF;              // chunk logits

    long ws_floats = (long)(ws_size / sizeof(float));
    long cap_rows = (ws_floats - DF) / LS;
    if (cap_rows > NS) cap_rows = NS;
    if (cap_rows < 1) cap_rows = 1;                 // last resort; guarded anyway
    int chunk = (cap_rows >= BM) ? (int)(cap_rows - (cap_rows % BM)) : (int)cap_rows;

    hipMemsetAsync(d_out, 0, (size_t)out_size * sizeof(float), stream);
    centroid_kernel<<<DF / 256, 256, 0, stream>>>(w, cen);

    for (int r0 = 0; r0 < NS; r0 += chunk) {
        int rows = (NS - r0 < chunk) ? (NS - r0) : chunk;
        dim3 grid((LS + BN - 1) / BN, (rows + BM - 1) / BM);
        gemm_kernel<<<grid, 256, 0, stream>>>(x, w, S, r0, rows);
        pass2_kernel<<<rows, 256, 0, stream>>>(S, x, w, cen, out, r0);
    }
}

// Round 4
// 696.775 us; speedup vs baseline: 2.9751x; 2.9751x over previous
//
#include <hip/hip_runtime.h>
#include <cmath>

#define NS 16384   // samples
#define LS 4096    // memory slots
#define DF 1024    // feature dim
#define SHRINK_T 0.0025f
#define EPS_T 1e-12f

using f16 = _Float16;
using f16x4 = __attribute__((ext_vector_type(4))) _Float16;
using f16x8 = __attribute__((ext_vector_type(8))) _Float16;
using f32x4 = __attribute__((ext_vector_type(4))) float;

// ---------------- K_split: f32 -> f16 hi + f16 lo residual ----------------
__global__ void split_kernel(const float* __restrict__ src,
                             f16* __restrict__ hi, f16* __restrict__ lo, int n4) {
    int i = blockIdx.x * 256 + threadIdx.x;
    if (i >= n4) return;
    float4 v = reinterpret_cast<const float4*>(src)[i];
    f16x4 h, l;
    h[0] = (f16)v.x; h[1] = (f16)v.y; h[2] = (f16)v.z; h[3] = (f16)v.w;
    l[0] = (f16)(v.x - (float)h[0]);
    l[1] = (f16)(v.y - (float)h[1]);
    l[2] = (f16)(v.z - (float)h[2]);
    l[3] = (f16)(v.w - (float)h[3]);
    reinterpret_cast<f16x4*>(hi)[i] = h;
    reinterpret_cast<f16x4*>(lo)[i] = l;
}

// ---------------- K0: centroid = mean(weight, axis=0) ----------------
__global__ void centroid_kernel(const float* __restrict__ w, float* __restrict__ cen) {
    int c = blockIdx.x * 256 + threadIdx.x;
    if (c >= DF) return;
    float acc = 0.f;
    for (int l = 0; l < LS; ++l) acc += w[(size_t)l * DF + c];
    cen[c] = acc * (1.0f / (float)LS);
}

// ---------------- K1: S = x @ w^T via 3-term f16-split MFMA ----------------
#define BM 128
#define BN 128
#define BK 32

#define GLOAD16(gptr, lptr)                                                    \
    __builtin_amdgcn_global_load_lds(                                          \
        (const __attribute__((address_space(1))) void*)(gptr),                 \
        (__attribute__((address_space(3))) void*)(lptr), 16, 0, 0)

__global__ __launch_bounds__(256) void gemm_f16_kernel(
    const f16* __restrict__ xh, const f16* __restrict__ xl,
    const f16* __restrict__ wh, const f16* __restrict__ wl,
    float* __restrict__ S, int r0, int rowsChunk)
{
    __shared__ __align__(16) f16 Ah[BM * BK];
    __shared__ __align__(16) f16 Al[BM * BK];
    __shared__ __align__(16) f16 Bh[BN * BK];
    __shared__ __align__(16) f16 Bl[BN * BK];

    const int t = threadIdx.x;
    const int lane = t & 63;
    const int wv = t >> 6;                 // wave id 0..3
    const int wr = (wv >> 1) * 64;         // wave row offset in tile
    const int wc = (wv & 1) * 64;          // wave col offset in tile
    const int rowBase = r0 + blockIdx.y * BM;
    const int colBase = blockIdx.x * BN;

    f32x4 acc[4][4];
#pragma unroll
    for (int m = 0; m < 4; ++m)
#pragma unroll
        for (int n = 0; n < 4; ++n)
            acc[m][n] = (f32x4){0.f, 0.f, 0.f, 0.f};

    const int fr = lane & 15;              // fragment row/col index
    const int fq = lane >> 4;              // k-quadrant / acc row group
    const int kq = fq * 8;                 // k element offset for frags

    for (int k0 = 0; k0 < DF; k0 += BK) {
        // ---- stage 4 tiles via global_load_lds (linear LDS, 16B/lane) ----
#pragma unroll
        for (int h = 0; h < 2; ++h) {
            const int sr = h * 64 + (t >> 2);       // row in tile 0..127
            const int cc = (t & 3) * 8;             // f16 col offset 0/8/16/24
            int ga = rowBase + sr; if (ga >= NS) ga = NS - 1;
            const int gb = colBase + sr;            // always < LS
            const int lbase = (h * 64 + wv * 16) * BK;   // wave-uniform
            GLOAD16(xh + (size_t)ga * DF + k0 + cc, &Ah[lbase]);
            GLOAD16(xl + (size_t)ga * DF + k0 + cc, &Al[lbase]);
            GLOAD16(wh + (size_t)gb * DF + k0 + cc, &Bh[lbase]);
            GLOAD16(wl + (size_t)gb * DF + k0 + cc, &Bl[lbase]);
        }
        __syncthreads();   // compiler emits vmcnt(0) drain before barrier

        // ---- LDS -> fragments (ds_read_b128 each) ----
        f16x8 amh[4], aml[4], bnh[4], bnl[4];
#pragma unroll
        for (int m = 0; m < 4; ++m) {
            const int r = wr + m * 16 + fr;
            amh[m] = *(const f16x8*)&Ah[r * BK + kq];
            aml[m] = *(const f16x8*)&Al[r * BK + kq];
        }
#pragma unroll
        for (int n = 0; n < 4; ++n) {
            const int c = wc + n * 16 + fr;
            bnh[n] = *(const f16x8*)&Bh[c * BK + kq];
            bnl[n] = *(const f16x8*)&Bl[c * BK + kq];
        }

        // ---- 3-term accumulate: hi*hi + hi*lo + lo*hi ----
#pragma unroll
        for (int m = 0; m < 4; ++m)
#pragma unroll
            for (int n = 0; n < 4; ++n) {
                acc[m][n] = __builtin_amdgcn_mfma_f32_16x16x32_f16(amh[m], bnh[n], acc[m][n], 0, 0, 0);
                acc[m][n] = __builtin_amdgcn_mfma_f32_16x16x32_f16(amh[m], bnl[n], acc[m][n], 0, 0, 0);
                acc[m][n] = __builtin_amdgcn_mfma_f32_16x16x32_f16(aml[m], bnh[n], acc[m][n], 0, 0, 0);
            }
        __syncthreads();
    }

    // ---- C write: row = (lane>>4)*4 + j, col = lane&15 (verified m89/m91) ----
#pragma unroll
    for (int m = 0; m < 4; ++m) {
        const int rbase = blockIdx.y * BM + wr + m * 16 + fq * 4;  // chunk-local
#pragma unroll
        for (int n = 0; n < 4; ++n) {
            const int cc = colBase + wc + n * 16 + fr;
#pragma unroll
            for (int j = 0; j < 4; ++j) {
                const int rr = rbase + j;
                if (rr < rowsChunk)
                    S[(size_t)rr * LS + cc] = acc[m][n][j];
            }
        }
    }
}

// ---------------- K2: per-row softmax/shrink/norm + all outputs (f32 out) ----------------
__global__ __launch_bounds__(256) void pass2_kernel(
    const float* __restrict__ S, const float* __restrict__ x,
    const float* __restrict__ w, const float* __restrict__ cen,
    float* __restrict__ out, int r0)
{
    constexpr int T = 256;
    constexpr int PER = LS / T;  // 16
    __shared__ float att_lds[LS];
    __shared__ float red[T];
    __shared__ int redi[T];

    const int t = threadIdx.x;
    const size_t row = (size_t)r0 + blockIdx.x;
    const float* srow = S + (size_t)blockIdx.x * (size_t)LS;

    float* const out_output = out;
    float* const out_att  = out + (size_t)NS * DF;
    float* const out_nl   = out + (size_t)NS * DF + (size_t)NS * LS;
    float* const out_nl2  = out + (size_t)2 * NS * DF + (size_t)NS * LS;
    float* const out_mask = out + (size_t)3 * NS * DF + (size_t)NS * LS;

    float sv[PER];
    float mx = -INFINITY;
#pragma unroll
    for (int i = 0; i < PER; ++i) {
        sv[i] = srow[i * T + t];
        mx = fmaxf(mx, sv[i]);
    }
    red[t] = mx;
    __syncthreads();
    for (int off = 128; off >= 1; off >>= 1) {
        if (t < off) red[t] = fmaxf(red[t], red[t + off]);
        __syncthreads();
    }
    const float m = red[0];
    __syncthreads();

    float zs = 0.f;
#pragma unroll
    for (int i = 0; i < PER; ++i) {
        sv[i] = expf(sv[i] - m);
        zs += sv[i];
    }
    red[t] = zs;
    __syncthreads();
    for (int off = 128; off >= 1; off >>= 1) {
        if (t < off) red[t] += red[t + off];
        __syncthreads();
    }
    const float Z = red[0];
    __syncthreads();

    float l1 = 0.f;
#pragma unroll
    for (int i = 0; i < PER; ++i) {
        float a = sv[i] / Z;
        float r = a - SHRINK_T;
        float v = (r > 0.f) ? (r * a) / (r + EPS_T) : 0.f;
        sv[i] = v;
        l1 += v;
    }
    red[t] = l1;
    __syncthreads();
    for (int off = 128; off >= 1; off >>= 1) {
        if (t < off) red[t] += red[t + off];
        __syncthreads();
    }
    const float nrm = fmaxf(red[0], EPS_T);
    __syncthreads();

    float bv = -INFINITY; int bi = LS;
    float mn = INFINITY;
#pragma unroll
    for (int i = 0; i < PER; ++i) {
        float vn = sv[i] / nrm;
        sv[i] = vn;
        int j = i * T + t;
        att_lds[j] = vn;
        out_att[row * LS + j] = vn;
        if (vn > bv) { bv = vn; bi = j; }
        mn = fminf(mn, vn);
    }
    __syncthreads();

    // argmax (first index on ties)
    red[t] = bv; redi[t] = bi;
    __syncthreads();
    for (int off = 128; off >= 1; off >>= 1) {
        if (t < off) {
            float ov = red[t + off]; int oi = redi[t + off];
            if (ov > red[t] || (ov == red[t] && oi < redi[t])) { red[t] = ov; redi[t] = oi; }
        }
        __syncthreads();
    }
    const int ind = redi[0];
    __syncthreads();

    red[t] = mn;
    __syncthreads();
    for (int off = 128; off >= 1; off >>= 1) {
        if (t < off) red[t] = fminf(red[t], red[t + off]);
        __syncthreads();
    }
    const float rowmin = red[0];
    __syncthreads();

    bv = -INFINITY; bi = LS;
#pragma unroll
    for (int i = 0; i < PER; ++i) {
        int j = i * T + t;
        float vv = (j == ind) ? rowmin : sv[i];
        if (vv > bv) { bv = vv; bi = j; }
    }
    red[t] = bv; redi[t] = bi;
    __syncthreads();
    for (int off = 128; off >= 1; off >>= 1) {
        if (t < off) {
            float ov = red[t + off]; int oi = redi[t + off];
            if (ov > red[t] || (ov == red[t] && oi < redi[t])) { red[t] = ov; redi[t] = oi; }
        }
        __syncthreads();
    }
    const int ind2 = redi[0];
    __syncthreads();

    // sparse output row via wave-uniform ballot over LDS
    const int lane = t & 63;
    float oa[4] = {0.f, 0.f, 0.f, 0.f};
    for (int k0 = 0; k0 < LS; k0 += 64) {
        float av = att_lds[k0 + lane];
        unsigned long long msk = __ballot(av > 0.f);
        while (msk) {
            int b = __ffsll((unsigned long long)msk) - 1;
            msk &= msk - 1;
            float vv = att_lds[k0 + b];
            const float* wr = w + (size_t)(k0 + b) * DF;
#pragma unroll
            for (int q = 0; q < 4; ++q) oa[q] = fmaf(vv, wr[t + T * q], oa[q]);
        }
    }
#pragma unroll
    for (int q = 0; q < 4; ++q)
        out_output[row * DF + t + T * q] = oa[q];

    const float* w1 = w + (size_t)ind * DF;
    const float* w2 = w + (size_t)ind2 * DF;
#pragma unroll
    for (int q = 0; q < 4; ++q) {
        out_nl[row * DF + t + T * q]  = w1[t + T * q];
        out_nl2[row * DF + t + T * q] = w2[t + T * q];
    }

    float ds = 0.f;
#pragma unroll
    for (int q = 0; q < 4; ++q) {
        float d = x[row * DF + t + T * q] - cen[t + T * q];
        ds = fmaf(d, d, ds);
    }
    red[t] = ds;
    __syncthreads();
    for (int off = 128; off >= 1; off >>= 1) {
        if (t < off) red[t] += red[t + off];
        __syncthreads();
    }
    if (t == 0) {
        float dist = sqrtf(red[0]);
        out_mask[row] = (dist < 1.0f) ? 1.0f : 0.0f;
    }
}

// ---------------- host ----------------
extern "C" void kernel_launch(void* const* d_in, const int* in_sizes, int n_in,
                              void* d_out, int out_size, void* d_ws, size_t ws_size,
                              hipStream_t stream)
{
    const float* x = (const float*)d_in[0];
    const float* w = (const float*)d_in[1];
    float* out = (float*)d_out;

    // workspace layout: cen | xh | xl | wh | wl | S-chunk
    float* cen = (float*)d_ws;                       // DF floats
    f16* xh = (f16*)(cen + DF);                      // NS*DF
    f16* xl = xh + (size_t)NS * DF;
    f16* wh = xl + (size_t)NS * DF;                  // LS*DF
    f16* wl = wh + (size_t)LS * DF;
    float* S = (float*)(wl + (size_t)LS * DF);       // remainder

    const size_t head_bytes = sizeof(float) * DF + (size_t)2 * 2 * NS * DF + (size_t)2 * 2 * LS * DF;
    long cap_rows = (long)((ws_size - head_bytes) / (sizeof(float) * LS));
    if (cap_rows > NS) cap_rows = NS;
    if (cap_rows < 1) cap_rows = 1;
    int chunk = (cap_rows >= BM) ? (int)(cap_rows - (cap_rows % BM)) : (int)cap_rows;

    split_kernel<<<(NS * DF / 4 + 255) / 256, 256, 0, stream>>>(x, xh, xl, NS * DF / 4);
    split_kernel<<<(LS * DF / 4 + 255) / 256, 256, 0, stream>>>(w, wh, wl, LS * DF / 4);
    centroid_kernel<<<DF / 256, 256, 0, stream>>>(w, cen);

    for (int r0 = 0; r0 < NS; r0 += chunk) {
        int rows = (NS - r0 < chunk) ? (NS - r0) : chunk;
        dim3 grid((LS + BN - 1) / BN, (rows + BM - 1) / BM);
        gemm_f16_kernel<<<grid, 256, 0, stream>>>(xh, xl, wh, wl, S, r0, rows);
        pass2_kernel<<<rows, 256, 0, stream>>>(S, x, w, cen, out, r0);
    }
}